// Round 9
// baseline (308.688 us; speedup 1.0000x reference)
//
#include <hip/hip_runtime.h>
#include <cstdint>
#include <cstddef>

// Problem constants
#define D_DIM 64
#define M_DIM 256
#define N_PTS 1024

typedef __attribute__((ext_vector_type(4))) float f32x4;
typedef __attribute__((ext_vector_type(2))) float f32x2;
typedef __attribute__((ext_vector_type(8))) short s16x8;

static __device__ __forceinline__ f32x2 pkfma(f32x2 a, f32x2 b, f32x2 c) {
#if __has_builtin(__builtin_elementwise_fma)
    return __builtin_elementwise_fma(a, b, c);
#else
    f32x2 r; r.x = fmaf(a.x, b.x, c.x); r.y = fmaf(a.y, b.y, c.y); return r;
#endif
}
static __device__ __forceinline__ f32x2 sp2(float s) {
    f32x2 r; r.x = s; r.y = s; return r;
}

static __device__ __forceinline__ float sp10f(float x) {
    // softplus(10x)/10, numerically stable, matches jax.nn.softplus
    float t = 10.f * x;
    return 0.1f * (fmaxf(t, 0.f) + log1pf(__expf(-fabsf(t))));
}

// packed branch-free tanh: 1 - 2/(exp(2x)+1) per component
static __device__ __forceinline__ f32x2 ftanh2(f32x2 x) {
    f32x2 x2 = x + x;
    f32x2 e;
    e.x = __expf(x2.x);
    e.y = __expf(x2.y);
    f32x2 ep = e + sp2(1.f);
    f32x2 r;
    r.x = __builtin_amdgcn_rcpf(ep.x);
    r.y = __builtin_amdgcn_rcpf(ep.y);
    return pkfma(sp2(-2.f), r, sp2(1.f));
}

static __device__ __forceinline__ unsigned short f2bf(float x) {
    unsigned u = __float_as_uint(x);
    u = u + 0x7FFFu + ((u >> 16) & 1u);   // round-to-nearest-even
    return (unsigned short)(u >> 16);
}
static __device__ __forceinline__ float bf2f(unsigned short h) {
    return __uint_as_float(((unsigned)h) << 16);
}

// rne-hi / trunc-lo split of one fp32 -> (rounded-u32, lo-float-bits)
static __device__ __forceinline__ void split1(float x, unsigned& uh, unsigned& ul) {
    unsigned u = __float_as_uint(x);
    uh = u + 0x7FFFu + ((u >> 16) & 1u);               // rne in upper 16
    ul = __float_as_uint(x - __uint_as_float(uh & 0xFFFF0000u));  // exact tail
}

// map global level-group index g (0..61) -> (raw pointer, local g)
static __device__ __forceinline__ const float* map_g(int g, const float* a0, const float* a1,
                                                     const float* a2, const float* a3,
                                                     const float* a4, int& lg) {
    if (g < 32) { lg = g;      return a0; }
    if (g < 48) { lg = g - 32; return a1; }
    if (g < 56) { lg = g - 48; return a2; }
    if (g < 60) { lg = g - 56; return a3; }
    lg = g - 60; return a4;
}

// ---------------- fused prep: X-transpose (blocks 0..15) + weight pack ----
__global__ __launch_bounds__(256) void k_prep2(
    const float* __restrict__ X, const float* __restrict__ wf,
    const float* __restrict__ wm, const float* __restrict__ wl,
    const float* __restrict__ b1, const float* __restrict__ bm,
    const float* __restrict__ bl, const float* __restrict__ af,
    const float* __restrict__ am, float* __restrict__ Wpack,
    float* __restrict__ Xt) {
    __shared__ float tile[64][65];
    const int t = threadIdx.x;
    if (blockIdx.x < 16) {
        const int n0 = blockIdx.x * 64;
#pragma unroll
        for (int i = 0; i < 4; i++) {
            const int f   = i * 256 + t;
            const int row = f >> 4;
            const int c4  = f & 15;
            float4 v = *(const float4*)(X + (size_t)(n0 + row) * 64 + c4 * 4);
            tile[row][c4 * 4 + 0] = v.x;
            tile[row][c4 * 4 + 1] = v.y;
            tile[row][c4 * 4 + 2] = v.z;
            tile[row][c4 * 4 + 3] = v.w;
        }
        __syncthreads();
#pragma unroll
        for (int i = 0; i < 4; i++) {
            const int f    = i * 256 + t;
            const int drow = f >> 4;
            const int c4   = f & 15;
            float4 v;
            v.x = tile[c4 * 4 + 0][drow];
            v.y = tile[c4 * 4 + 1][drow];
            v.z = tile[c4 * 4 + 2][drow];
            v.w = tile[c4 * 4 + 3][drow];
            *(float4*)(Xt + (size_t)drow * 1024 + n0 + c4 * 4) = v;
        }
        return;
    }
    const int id = (blockIdx.x - 16) * 256 + t;  // dm chain id, 0..16383
    if (id >= 16384) return;
    float r[48];
#pragma unroll
    for (int q = 0; q < 48; q++) r[q] = 0.f;
#pragma unroll
    for (int q = 0; q < 3; q++) {
        r[0 + q] = sp10f(wf[id * 3 + q]);
        r[3 + q] = b1[id * 3 + q];
        r[6 + q] = tanhf(af[id * 3 + q]);
        r[39 + q] = sp10f(wl[id * 3 + q]);
    }
#pragma unroll
    for (int l = 0; l < 2; l++) {
        const size_t b9 = ((size_t)l * 16384 + id) * 9;
        const size_t b3 = ((size_t)l * 16384 + id) * 3;
#pragma unroll
        for (int q = 0; q < 9; q++) r[9 + l * 15 + q] = sp10f(wm[b9 + q]);
#pragma unroll
        for (int q = 0; q < 3; q++) {
            r[18 + l * 15 + q] = bm[b3 + q];
            r[21 + l * 15 + q] = tanhf(am[b3 + q]);
        }
    }
    r[42] = bl[id];
    float4* o = (float4*)(Wpack + (size_t)id * 48);
#pragma unroll
    for (int q = 0; q < 12; q++) o[q] = ((float4*)r)[q];
}

// ---------------- tiled transpose + sp10 + bf16 hi/lo split --------------
__global__ __launch_bounds__(256) void k_tr(const float* __restrict__ a0,
                                            const float* __restrict__ a1,
                                            const float* __restrict__ a2,
                                            const float* __restrict__ a3,
                                            const float* __restrict__ a4,
                                            unsigned short* __restrict__ Anth,
                                            unsigned short* __restrict__ Antl) {
    __shared__ float tile[64][65];
    const int g  = blockIdx.z;
    const int m0 = blockIdx.x * 64;
    const int k0 = blockIdx.y * 64;
    int lg;
    const float* A  = map_g(g, a0, a1, a2, a3, a4, lg);
    const float* Ag = A + (size_t)lg * 65536;
    const int t = threadIdx.x;

#pragma unroll
    for (int i = 0; i < 4; i++) {
        const int f   = i * 256 + t;
        const int row = f >> 4;
        const int c4  = f & 15;
        float4 v = *(const float4*)(Ag + (size_t)(m0 + row) * 256 + k0 + c4 * 4);
        tile[row][c4 * 4 + 0] = v.x;
        tile[row][c4 * 4 + 1] = v.y;
        tile[row][c4 * 4 + 2] = v.z;
        tile[row][c4 * 4 + 3] = v.w;
    }
    __syncthreads();

#pragma unroll
    for (int i = 0; i < 4; i++) {
        const int f    = i * 256 + t;
        const int krow = f >> 4;
        const int c4   = f & 15;
        float v0 = sp10f(tile[c4 * 4 + 0][krow]);
        float v1 = sp10f(tile[c4 * 4 + 1][krow]);
        float v2 = sp10f(tile[c4 * 4 + 2][krow]);
        float v3 = sp10f(tile[c4 * 4 + 3][krow]);
        unsigned short h0 = f2bf(v0), h1 = f2bf(v1), h2 = f2bf(v2), h3 = f2bf(v3);
        ushort4 hi, lo;
        hi.x = h0; hi.y = h1; hi.z = h2; hi.w = h3;
        lo.x = f2bf(v0 - bf2f(h0));
        lo.y = f2bf(v1 - bf2f(h1));
        lo.z = f2bf(v2 - bf2f(h2));
        lo.w = f2bf(v3 - bf2f(h3));
        const size_t dst = (size_t)g * 65536 + (size_t)(k0 + krow) * 256 + m0 + c4 * 4;
        *(ushort4*)(Anth + dst) = hi;
        *(ushort4*)(Antl + dst) = lo;
    }
}

// column sums (over m) from transposed hi/lo rows.
__global__ void k_csum_t(const unsigned short* __restrict__ Anth,
                         const unsigned short* __restrict__ Antl,
                         float* __restrict__ csum) {
    const int g    = blockIdx.x;
    const int w    = threadIdx.x >> 6;
    const int lane = threadIdx.x & 63;
    const int k    = blockIdx.y * 4 + w;
    const size_t base = (size_t)g * 65536 + k * 256 + lane * 4;
    uint2 vh = *(const uint2*)(Anth + base);
    uint2 vl = *(const uint2*)(Antl + base);
    float s = 0.f;
    s += bf2f((unsigned short)(vh.x & 0xFFFFu)) + bf2f((unsigned short)(vh.x >> 16));
    s += bf2f((unsigned short)(vh.y & 0xFFFFu)) + bf2f((unsigned short)(vh.y >> 16));
    s += bf2f((unsigned short)(vl.x & 0xFFFFu)) + bf2f((unsigned short)(vl.x >> 16));
    s += bf2f((unsigned short)(vl.y & 0xFFFFu)) + bf2f((unsigned short)(vl.y >> 16));
    for (int off = 32; off > 0; off >>= 1) s += __shfl_down(s, off);
    if (lane == 0) csum[g * 256 + k] = s;
}

// ---------------- phase 1: wave = one (d,m) chain, 2 n per lane (packed) -
// Output written PRE-SPLIT as bf16 hi/lo (P0h/P0l); L0 stage-A is pure copy.
__global__ __launch_bounds__(512, 1) void k_phase1(
    const float* __restrict__ Xt, const float* __restrict__ Wpack,
    unsigned short* __restrict__ P0h, unsigned short* __restrict__ P0l) {
    __shared__ float sT[128][65];
    __shared__ float sXd[2][128];
    const int j  = blockIdx.x;        // d-pair
    const int mc = blockIdx.y;        // m-chunk of 64
    const int n0 = blockIdx.z * 128;  // n base
    const int t  = threadIdx.x;
    const int w    = __builtin_amdgcn_readfirstlane(t >> 6);
    const int lane = t & 63;

    if (t < 256)
        sXd[t >> 7][t & 127] = Xt[(size_t)(2 * j + (t >> 7)) * 1024 + n0 + (t & 127)];
    __syncthreads();

    const f32x2 one2 = sp2(1.f);

#pragma unroll 1
    for (int i = 0; i < 8; i++) {
        const int mm = w * 8 + i;
        const int m  = mc * 64 + mm;
        f32x2 p0;
#pragma unroll 1
        for (int e = 0; e < 2; e++) {
            const float* __restrict__ rp =
                Wpack + (size_t)(((2 * j + e) << 8) + m) * 48;
            float W1a[3], B1a[3], T1a[3], Wm[2][9], Bm[2][3], Tm[2][3], Wla[3];
#pragma unroll
            for (int r = 0; r < 3; r++) {
                W1a[r] = rp[r];
                B1a[r] = rp[3 + r];
                T1a[r] = rp[6 + r];
                Bm[0][r] = rp[18 + r];
                Tm[0][r] = rp[21 + r];
                Bm[1][r] = rp[33 + r];
                Tm[1][r] = rp[36 + r];
                Wla[r] = rp[39 + r];
            }
#pragma unroll
            for (int q = 0; q < 9; q++) {
                Wm[0][q] = rp[9 + q];
                Wm[1][q] = rp[24 + q];
            }
            const float Bla = rp[42];

            f32x2 x;
            x.x = sXd[e][lane];
            x.y = sXd[e][64 + lane];
            f32x2 phi[3], pd[3];
#pragma unroll
            for (int r = 0; r < 3; r++) {
                f32x2 z  = pkfma(x, sp2(W1a[r]), sp2(B1a[r]));
                f32x2 tz = ftanh2(z);
                f32x2 ta = sp2(T1a[r]);
                pd[r]  = sp2(W1a[r]) * pkfma(ta, pkfma(-tz, tz, one2), one2);
                phi[r] = pkfma(tz, ta, z);
            }
#pragma unroll
            for (int l = 0; l < 2; l++) {
                f32x2 nphi[3], npd[3];
#pragma unroll
                for (int q = 0; q < 3; q++) {
                    f32x2 z  = sp2(Bm[l][q]);
                    f32x2 dp = sp2(0.f);
#pragma unroll
                    for (int r = 0; r < 3; r++) {
                        f32x2 wv = sp2(Wm[l][r * 3 + q]);
                        z  = pkfma(phi[r], wv, z);
                        dp = pkfma(pd[r],  wv, dp);
                    }
                    f32x2 tz = ftanh2(z);
                    f32x2 ta = sp2(Tm[l][q]);
                    nphi[q] = pkfma(tz, ta, z);
                    npd[q]  = dp * pkfma(ta, pkfma(-tz, tz, one2), one2);
                }
#pragma unroll
                for (int q = 0; q < 3; q++) { phi[q] = nphi[q]; pd[q] = npd[q]; }
            }
            f32x2 z  = sp2(Bla);
            f32x2 dp = sp2(0.f);
#pragma unroll
            for (int r = 0; r < 3; r++) {
                f32x2 wv = sp2(Wla[r]);
                z  = pkfma(phi[r], wv, z);
                dp = pkfma(pd[r],  wv, dp);
            }
            f32x2 s;
            s.x = __builtin_amdgcn_rcpf(1.f + __expf(-z.x));
            s.y = __builtin_amdgcn_rcpf(1.f + __expf(-z.y));
            f32x2 prod = dp * s * (one2 - s);
            if (e == 0) {
                p0 = prod;
            } else {
                sT[lane][mm]      = p0.x * prod.x;
                sT[64 + lane][mm] = p0.y * prod.y;
            }
        }
    }
    __syncthreads();

    // cooperative coalesced write: sT (128 n x 64 m) -> P0h/P0l[j][n][m]
    const size_t base = ((size_t)j * N_PTS + n0) * M_DIM + mc * 64;
#pragma unroll
    for (int it = 0; it < 4; it++) {
        const int idx = it * 512 + t;
        const int row = idx >> 4;
        const int c4  = idx & 15;
        float4 v;
        v.x = sT[row][c4 * 4 + 0];
        v.y = sT[row][c4 * 4 + 1];
        v.z = sT[row][c4 * 4 + 2];
        v.w = sT[row][c4 * 4 + 3];
        unsigned uh0, ul0, uh1, ul1, uh2, ul2, uh3, ul3;
        split1(v.x, uh0, ul0);
        split1(v.y, uh1, ul1);
        split1(v.z, uh2, ul2);
        split1(v.w, uh3, ul3);
        uint2 hp, lp;
        hp.x = __builtin_amdgcn_perm(uh1, uh0, 0x07060302u);
        hp.y = __builtin_amdgcn_perm(uh3, uh2, 0x07060302u);
        lp.x = __builtin_amdgcn_perm(ul1, ul0, 0x07060302u);
        lp.y = __builtin_amdgcn_perm(ul3, ul2, 0x07060302u);
        *(uint2*)(P0h + base + (size_t)row * M_DIM + c4 * 4) = hp;
        *(uint2*)(P0l + base + (size_t)row * M_DIM + c4 * 4) = lp;
    }
}

// ---------------- HT level: PAIR-FUSED 64x64 GEMM ------------------------
// For pair q: computes C_g = (T[g]·An[g]) / csum[g] for g = 2q, 2q+1 with
// two sequential K-loops (identical fragment mapping), then writes the
// ELEMENTWISE PRODUCT C_{2q}*C_{2q+1} — presplit bf16 hi/lo (or fp32 when
// LAST). All inputs are presplit hi/lo -> stage is a pure uint4 copy.
// grid (16 n-tiles, 4 k-tiles, pairs), 256 thr = 4 waves (2x2), 20 KB LDS.
#define LDST 40  // LDS row stride in bf16 elems (32 + 8 pad = 80 B)

template <int LAST>
__global__ __launch_bounds__(256, 4) void k_pair64(
    const unsigned short* __restrict__ Th, const unsigned short* __restrict__ Tl,
    const unsigned short* __restrict__ Bh, const unsigned short* __restrict__ Bl,
    const float* __restrict__ csum,
    unsigned short* __restrict__ Oh, unsigned short* __restrict__ Ol,
    float* __restrict__ Of) {
    __shared__ unsigned short sAh[64 * LDST];
    __shared__ unsigned short sAl[64 * LDST];
    __shared__ unsigned short sBh[64 * LDST];
    __shared__ unsigned short sBl[64 * LDST];

    const int q  = blockIdx.z;
    const int n0 = blockIdx.x * 64;
    const int k0 = blockIdx.y * 64;

    const int tid  = threadIdx.x;
    const int lane = tid & 63;
    const int w    = tid >> 6;
    const int wr   = w >> 1;   // n half (32)
    const int wc   = w & 1;    // k half (32)
    const int lr   = lane & 15;
    const int lk   = lane >> 4;

    // staging addresses (same every kb)
    const int srow = tid >> 2;   // 0..63
    const int sseg = tid & 3;    // 0..3 (8 ushorts each)

    f32x4 acc[2][2][2];
#pragma unroll
    for (int gi = 0; gi < 2; gi++)
#pragma unroll
        for (int a = 0; a < 2; a++)
#pragma unroll
            for (int b = 0; b < 2; b++) acc[gi][a][b] = (f32x4){0.f, 0.f, 0.f, 0.f};

#pragma unroll 1
    for (int gi = 0; gi < 2; gi++) {
        const int g = 2 * q + gi;
        const unsigned short* Thg = Th + (size_t)g * N_PTS * 256;
        const unsigned short* Tlg = Tl + (size_t)g * N_PTS * 256;
        const unsigned short* Bhg = Bh + (size_t)g * 65536;
        const unsigned short* Blg = Bl + (size_t)g * 65536;

        for (int kb = 0; kb < 256; kb += 32) {
            const size_t srcA = (size_t)(n0 + srow) * 256 + kb + sseg * 8;
            const size_t srcB = (size_t)(k0 + srow) * 256 + kb + sseg * 8;
            *(uint4*)&sAh[srow * LDST + sseg * 8] = *(const uint4*)(Thg + srcA);
            *(uint4*)&sAl[srow * LDST + sseg * 8] = *(const uint4*)(Tlg + srcA);
            *(uint4*)&sBh[srow * LDST + sseg * 8] = *(const uint4*)(Bhg + srcB);
            *(uint4*)&sBl[srow * LDST + sseg * 8] = *(const uint4*)(Blg + srcB);
            __syncthreads();

            s16x8 ah[2], al[2], bh[2], bl[2];
#pragma unroll
            for (int nt = 0; nt < 2; nt++) {
                const int off = (wr * 32 + nt * 16 + lr) * LDST + lk * 8;
                ah[nt] = *(const s16x8*)&sAh[off];
                al[nt] = *(const s16x8*)&sAl[off];
            }
#pragma unroll
            for (int kt = 0; kt < 2; kt++) {
                const int off = (wc * 32 + kt * 16 + lr) * LDST + lk * 8;
                bh[kt] = *(const s16x8*)&sBh[off];
                bl[kt] = *(const s16x8*)&sBl[off];
            }
#pragma unroll
            for (int nt = 0; nt < 2; nt++)
#pragma unroll
                for (int kt = 0; kt < 2; kt++) {
                    acc[gi][nt][kt] = __builtin_amdgcn_mfma_f32_16x16x32_bf16(ah[nt], bh[kt], acc[gi][nt][kt], 0, 0, 0);
                    acc[gi][nt][kt] = __builtin_amdgcn_mfma_f32_16x16x32_bf16(ah[nt], bl[kt], acc[gi][nt][kt], 0, 0, 0);
                    acc[gi][nt][kt] = __builtin_amdgcn_mfma_f32_16x16x32_bf16(al[nt], bh[kt], acc[gi][nt][kt], 0, 0, 0);
                }
            __syncthreads();
        }
    }

    // epilogue: normalize each group, multiply, write product
#pragma unroll
    for (int kt = 0; kt < 2; kt++) {
        const int col = k0 + wc * 32 + kt * 16 + lr;
        const float inv0 = 1.0f / csum[(2 * q) * 256 + col];
        const float inv1 = 1.0f / csum[(2 * q + 1) * 256 + col];
#pragma unroll
        for (int nt = 0; nt < 2; nt++) {
            const int rbase = n0 + wr * 32 + nt * 16 + lk * 4;
#pragma unroll
            for (int r = 0; r < 4; r++) {
                const float v = (acc[0][nt][kt][r] * inv0) * (acc[1][nt][kt][r] * inv1);
                const size_t dst = ((size_t)q * N_PTS + rbase + r) * 256 + col;
                if (LAST) {
                    Of[dst] = v;
                } else {
                    unsigned uh, ul;
                    split1(v, uh, ul);
                    Oh[dst] = (unsigned short)(uh >> 16);
                    Ol[dst] = (unsigned short)(ul >> 16);
                }
            }
        }
    }
}

// ---------------- level 5: normalized dot over the final product ---------
__global__ void k_l5(const float* __restrict__ Tin, const float* __restrict__ a5,
                     float* __restrict__ out) {
    const int n = blockIdx.x;
    const int m = threadIdx.x;
    __shared__ float sv[256], sw[256];
    float w = sp10f(a5[m]);
    float v = Tin[(size_t)n * 256 + m] * w;
    sv[m] = v;
    sw[m] = w;
    __syncthreads();
    for (int s = 128; s > 0; s >>= 1) {
        if (m < s) { sv[m] += sv[m + s]; sw[m] += sw[m + s]; }
        __syncthreads();
    }
    if (m == 0) out[n] = sv[0] / sw[0];
}

extern "C" void kernel_launch(void* const* d_in, const int* in_sizes, int n_in,
                              void* d_out, int out_size, void* d_ws, size_t ws_size,
                              hipStream_t stream) {
    const float* X  = (const float*)d_in[0];
    const float* wf = (const float*)d_in[1];
    const float* wm = (const float*)d_in[2];
    const float* wl = (const float*)d_in[3];
    const float* b1 = (const float*)d_in[4];
    const float* bm = (const float*)d_in[5];
    const float* bl = (const float*)d_in[6];
    const float* af = (const float*)d_in[7];
    const float* am = (const float*)d_in[8];
    const float* a0 = (const float*)d_in[9];
    const float* a1 = (const float*)d_in[10];
    const float* a2 = (const float*)d_in[11];
    const float* a3 = (const float*)d_in[12];
    const float* a4 = (const float*)d_in[13];
    const float* a5 = (const float*)d_in[14];
    float* out = (float*)d_out;

    const size_t NM = (size_t)N_PTS * M_DIM;   // 262144
    float* ws    = (float*)d_ws;
    float* Wpack = ws;                                 // 786432 f
    float* Xt    = Wpack + 786432;                     // 65536 f
    float* csum  = Xt + 65536;                         // 15872 f
    float* Ffin  = csum + 15872;                       // 262144 f
    unsigned short* Anth = (unsigned short*)(Ffin + NM);     // 62*65536 us
    unsigned short* Antl = Anth + (size_t)62 * 65536;        // 62*65536 us
    unsigned short* P0h  = Antl + (size_t)62 * 65536;        // 32*NM us
    unsigned short* P0l  = P0h + 32 * NM;                    // 32*NM us
    unsigned short* Q0h  = P0l + 32 * NM;                    // 16*NM us
    unsigned short* Q0l  = Q0h + 16 * NM;                    // 16*NM us
    unsigned short* Q1h  = Q0l + 16 * NM;                    // 8*NM us
    unsigned short* Q1l  = Q1h + 8 * NM;                     // 8*NM us
    unsigned short* Q2h  = Q1l + 8 * NM;                     // 4*NM us
    unsigned short* Q2l  = Q2h + 4 * NM;                     // 4*NM us
    unsigned short* Q3h  = Q2l + 4 * NM;                     // 2*NM us
    unsigned short* Q3l  = Q3h + 2 * NM;                     // 2*NM us

    k_prep2<<<80, 256, 0, stream>>>(X, wf, wm, wl, b1, bm, bl, af, am, Wpack, Xt);
    k_tr<<<dim3(4, 4, 62), 256, 0, stream>>>(a0, a1, a2, a3, a4, Anth, Antl);
    k_csum_t<<<dim3(62, 64), 256, 0, stream>>>(Anth, Antl, csum);
    k_phase1<<<dim3(32, 4, 8), 512, 0, stream>>>(Xt, Wpack, P0h, P0l);

    // HT levels, pair-fused: each writes the pair product, presplit hi/lo
    k_pair64<0><<<dim3(16, 4, 16), 256, 0, stream>>>(P0h, P0l, Anth, Antl,
                                                     csum, Q0h, Q0l, nullptr);
    k_pair64<0><<<dim3(16, 4, 8), 256, 0, stream>>>(Q0h, Q0l,
                                                    Anth + (size_t)32 * 65536,
                                                    Antl + (size_t)32 * 65536,
                                                    csum + 32 * 256, Q1h, Q1l, nullptr);
    k_pair64<0><<<dim3(16, 4, 4), 256, 0, stream>>>(Q1h, Q1l,
                                                    Anth + (size_t)48 * 65536,
                                                    Antl + (size_t)48 * 65536,
                                                    csum + 48 * 256, Q2h, Q2l, nullptr);
    k_pair64<0><<<dim3(16, 4, 2), 256, 0, stream>>>(Q2h, Q2l,
                                                    Anth + (size_t)56 * 65536,
                                                    Antl + (size_t)56 * 65536,
                                                    csum + 56 * 256, Q3h, Q3l, nullptr);
    k_pair64<1><<<dim3(16, 4, 1), 256, 0, stream>>>(Q3h, Q3l,
                                                    Anth + (size_t)60 * 65536,
                                                    Antl + (size_t)60 * 65536,
                                                    csum + 60 * 256, nullptr, nullptr, Ffin);
    // level 5
    k_l5<<<N_PTS, 256, 0, stream>>>(Ffin, a5, out);
}

// Round 10
// 183.320 us; speedup vs baseline: 1.6839x; 1.6839x over previous
//
#include <hip/hip_runtime.h>
#include <cstdint>
#include <cstddef>

// Problem constants
#define D_DIM 64
#define M_DIM 256
#define N_PTS 1024

typedef __attribute__((ext_vector_type(4))) float f32x4;
typedef __attribute__((ext_vector_type(2))) float f32x2;
typedef __attribute__((ext_vector_type(8))) short s16x8;

static __device__ __forceinline__ f32x2 pkfma(f32x2 a, f32x2 b, f32x2 c) {
#if __has_builtin(__builtin_elementwise_fma)
    return __builtin_elementwise_fma(a, b, c);
#else
    f32x2 r; r.x = fmaf(a.x, b.x, c.x); r.y = fmaf(a.y, b.y, c.y); return r;
#endif
}
static __device__ __forceinline__ f32x2 sp2(float s) {
    f32x2 r; r.x = s; r.y = s; return r;
}

static __device__ __forceinline__ float sp10f(float x) {
    // softplus(10x)/10, numerically stable, matches jax.nn.softplus
    float t = 10.f * x;
    return 0.1f * (fmaxf(t, 0.f) + log1pf(__expf(-fabsf(t))));
}

// packed branch-free tanh: 1 - 2/(exp(2x)+1) per component
static __device__ __forceinline__ f32x2 ftanh2(f32x2 x) {
    f32x2 x2 = x + x;
    f32x2 e;
    e.x = __expf(x2.x);
    e.y = __expf(x2.y);
    f32x2 ep = e + sp2(1.f);
    f32x2 r;
    r.x = __builtin_amdgcn_rcpf(ep.x);
    r.y = __builtin_amdgcn_rcpf(ep.y);
    return pkfma(sp2(-2.f), r, sp2(1.f));
}

static __device__ __forceinline__ unsigned short f2bf(float x) {
    unsigned u = __float_as_uint(x);
    u = u + 0x7FFFu + ((u >> 16) & 1u);   // round-to-nearest-even
    return (unsigned short)(u >> 16);
}
static __device__ __forceinline__ float bf2f(unsigned short h) {
    return __uint_as_float(((unsigned)h) << 16);
}

// rne-hi / trunc-lo split of one fp32 -> (rounded-u32, lo-float-bits)
static __device__ __forceinline__ void split1(float x, unsigned& uh, unsigned& ul) {
    unsigned u = __float_as_uint(x);
    uh = u + 0x7FFFu + ((u >> 16) & 1u);               // rne in upper 16
    ul = __float_as_uint(x - __uint_as_float(uh & 0xFFFF0000u));  // exact tail
}

// map global level-group index g (0..61) -> (raw pointer, local g)
static __device__ __forceinline__ const float* map_g(int g, const float* a0, const float* a1,
                                                     const float* a2, const float* a3,
                                                     const float* a4, int& lg) {
    if (g < 32) { lg = g;      return a0; }
    if (g < 48) { lg = g - 32; return a1; }
    if (g < 56) { lg = g - 48; return a2; }
    if (g < 60) { lg = g - 56; return a3; }
    lg = g - 60; return a4;
}

// ---------------- fused prep: X-transpose (blocks 0..15) + weight pack ----
__global__ __launch_bounds__(256) void k_prep2(
    const float* __restrict__ X, const float* __restrict__ wf,
    const float* __restrict__ wm, const float* __restrict__ wl,
    const float* __restrict__ b1, const float* __restrict__ bm,
    const float* __restrict__ bl, const float* __restrict__ af,
    const float* __restrict__ am, float* __restrict__ Wpack,
    float* __restrict__ Xt) {
    __shared__ float tile[64][65];
    const int t = threadIdx.x;
    if (blockIdx.x < 16) {
        const int n0 = blockIdx.x * 64;
#pragma unroll
        for (int i = 0; i < 4; i++) {
            const int f   = i * 256 + t;
            const int row = f >> 4;
            const int c4  = f & 15;
            float4 v = *(const float4*)(X + (size_t)(n0 + row) * 64 + c4 * 4);
            tile[row][c4 * 4 + 0] = v.x;
            tile[row][c4 * 4 + 1] = v.y;
            tile[row][c4 * 4 + 2] = v.z;
            tile[row][c4 * 4 + 3] = v.w;
        }
        __syncthreads();
#pragma unroll
        for (int i = 0; i < 4; i++) {
            const int f    = i * 256 + t;
            const int drow = f >> 4;
            const int c4   = f & 15;
            float4 v;
            v.x = tile[c4 * 4 + 0][drow];
            v.y = tile[c4 * 4 + 1][drow];
            v.z = tile[c4 * 4 + 2][drow];
            v.w = tile[c4 * 4 + 3][drow];
            *(float4*)(Xt + (size_t)drow * 1024 + n0 + c4 * 4) = v;
        }
        return;
    }
    const int id = (blockIdx.x - 16) * 256 + t;  // dm chain id, 0..16383
    if (id >= 16384) return;
    float r[48];
#pragma unroll
    for (int q = 0; q < 48; q++) r[q] = 0.f;
#pragma unroll
    for (int q = 0; q < 3; q++) {
        r[0 + q] = sp10f(wf[id * 3 + q]);
        r[3 + q] = b1[id * 3 + q];
        r[6 + q] = tanhf(af[id * 3 + q]);
        r[39 + q] = sp10f(wl[id * 3 + q]);
    }
#pragma unroll
    for (int l = 0; l < 2; l++) {
        const size_t b9 = ((size_t)l * 16384 + id) * 9;
        const size_t b3 = ((size_t)l * 16384 + id) * 3;
#pragma unroll
        for (int q = 0; q < 9; q++) r[9 + l * 15 + q] = sp10f(wm[b9 + q]);
#pragma unroll
        for (int q = 0; q < 3; q++) {
            r[18 + l * 15 + q] = bm[b3 + q];
            r[21 + l * 15 + q] = tanhf(am[b3 + q]);
        }
    }
    r[42] = bl[id];
    float4* o = (float4*)(Wpack + (size_t)id * 48);
#pragma unroll
    for (int q = 0; q < 12; q++) o[q] = ((float4*)r)[q];
}

// ---------------- tiled transpose + sp10 + bf16 hi/lo split --------------
__global__ __launch_bounds__(256) void k_tr(const float* __restrict__ a0,
                                            const float* __restrict__ a1,
                                            const float* __restrict__ a2,
                                            const float* __restrict__ a3,
                                            const float* __restrict__ a4,
                                            unsigned short* __restrict__ Anth,
                                            unsigned short* __restrict__ Antl) {
    __shared__ float tile[64][65];
    const int g  = blockIdx.z;
    const int m0 = blockIdx.x * 64;
    const int k0 = blockIdx.y * 64;
    int lg;
    const float* A  = map_g(g, a0, a1, a2, a3, a4, lg);
    const float* Ag = A + (size_t)lg * 65536;
    const int t = threadIdx.x;

#pragma unroll
    for (int i = 0; i < 4; i++) {
        const int f   = i * 256 + t;
        const int row = f >> 4;
        const int c4  = f & 15;
        float4 v = *(const float4*)(Ag + (size_t)(m0 + row) * 256 + k0 + c4 * 4);
        tile[row][c4 * 4 + 0] = v.x;
        tile[row][c4 * 4 + 1] = v.y;
        tile[row][c4 * 4 + 2] = v.z;
        tile[row][c4 * 4 + 3] = v.w;
    }
    __syncthreads();

#pragma unroll
    for (int i = 0; i < 4; i++) {
        const int f    = i * 256 + t;
        const int krow = f >> 4;
        const int c4   = f & 15;
        float v0 = sp10f(tile[c4 * 4 + 0][krow]);
        float v1 = sp10f(tile[c4 * 4 + 1][krow]);
        float v2 = sp10f(tile[c4 * 4 + 2][krow]);
        float v3 = sp10f(tile[c4 * 4 + 3][krow]);
        unsigned short h0 = f2bf(v0), h1 = f2bf(v1), h2 = f2bf(v2), h3 = f2bf(v3);
        ushort4 hi, lo;
        hi.x = h0; hi.y = h1; hi.z = h2; hi.w = h3;
        lo.x = f2bf(v0 - bf2f(h0));
        lo.y = f2bf(v1 - bf2f(h1));
        lo.z = f2bf(v2 - bf2f(h2));
        lo.w = f2bf(v3 - bf2f(h3));
        const size_t dst = (size_t)g * 65536 + (size_t)(k0 + krow) * 256 + m0 + c4 * 4;
        *(ushort4*)(Anth + dst) = hi;
        *(ushort4*)(Antl + dst) = lo;
    }
}

// column sums (over m) from transposed hi/lo rows.
__global__ void k_csum_t(const unsigned short* __restrict__ Anth,
                         const unsigned short* __restrict__ Antl,
                         float* __restrict__ csum) {
    const int g    = blockIdx.x;
    const int w    = threadIdx.x >> 6;
    const int lane = threadIdx.x & 63;
    const int k    = blockIdx.y * 4 + w;
    const size_t base = (size_t)g * 65536 + k * 256 + lane * 4;
    uint2 vh = *(const uint2*)(Anth + base);
    uint2 vl = *(const uint2*)(Antl + base);
    float s = 0.f;
    s += bf2f((unsigned short)(vh.x & 0xFFFFu)) + bf2f((unsigned short)(vh.x >> 16));
    s += bf2f((unsigned short)(vh.y & 0xFFFFu)) + bf2f((unsigned short)(vh.y >> 16));
    s += bf2f((unsigned short)(vl.x & 0xFFFFu)) + bf2f((unsigned short)(vl.x >> 16));
    s += bf2f((unsigned short)(vl.y & 0xFFFFu)) + bf2f((unsigned short)(vl.y >> 16));
    for (int off = 32; off > 0; off >>= 1) s += __shfl_down(s, off);
    if (lane == 0) csum[g * 256 + k] = s;
}

// ---------------- phase 1: wave = one (d,m) chain, 2 n per lane (packed) -
// (i,e) loops flattened to one 16-iter loop with unroll 2 so the SGPR
// weight-record loads of iteration k+1 overlap iteration k's compute
// (round-8 residual: serial s_load latency per iteration).
__global__ __launch_bounds__(512, 1) void k_phase1(
    const float* __restrict__ Xt, const float* __restrict__ Wpack,
    unsigned short* __restrict__ P0h, unsigned short* __restrict__ P0l) {
    __shared__ float sT[128][65];
    __shared__ float sXd[2][128];
    const int j  = blockIdx.x;        // d-pair
    const int mc = blockIdx.y;        // m-chunk of 64
    const int n0 = blockIdx.z * 128;  // n base
    const int t  = threadIdx.x;
    const int w    = __builtin_amdgcn_readfirstlane(t >> 6);
    const int lane = t & 63;

    if (t < 256)
        sXd[t >> 7][t & 127] = Xt[(size_t)(2 * j + (t >> 7)) * 1024 + n0 + (t & 127)];
    __syncthreads();

    f32x2 xe0, xe1;
    xe0.x = sXd[0][lane]; xe0.y = sXd[0][64 + lane];
    xe1.x = sXd[1][lane]; xe1.y = sXd[1][64 + lane];

    const f32x2 one2 = sp2(1.f);
    f32x2 p0;

#pragma unroll 2
    for (int it = 0; it < 16; it++) {
        const int i  = it >> 1;
        const int e  = it & 1;
        const int mm = w * 8 + i;
        const int m  = mc * 64 + mm;
        const float* __restrict__ rp =
            Wpack + (size_t)(((2 * j + e) << 8) + m) * 48;
        float W1a[3], B1a[3], T1a[3], Wm[2][9], Bm[2][3], Tm[2][3], Wla[3];
#pragma unroll
        for (int r = 0; r < 3; r++) {
            W1a[r] = rp[r];
            B1a[r] = rp[3 + r];
            T1a[r] = rp[6 + r];
            Bm[0][r] = rp[18 + r];
            Tm[0][r] = rp[21 + r];
            Bm[1][r] = rp[33 + r];
            Tm[1][r] = rp[36 + r];
            Wla[r] = rp[39 + r];
        }
#pragma unroll
        for (int q = 0; q < 9; q++) {
            Wm[0][q] = rp[9 + q];
            Wm[1][q] = rp[24 + q];
        }
        const float Bla = rp[42];

        const f32x2 x = e ? xe1 : xe0;
        f32x2 phi[3], pd[3];
#pragma unroll
        for (int r = 0; r < 3; r++) {
            f32x2 z  = pkfma(x, sp2(W1a[r]), sp2(B1a[r]));
            f32x2 tz = ftanh2(z);
            f32x2 ta = sp2(T1a[r]);
            pd[r]  = sp2(W1a[r]) * pkfma(ta, pkfma(-tz, tz, one2), one2);
            phi[r] = pkfma(tz, ta, z);
        }
#pragma unroll
        for (int l = 0; l < 2; l++) {
            f32x2 nphi[3], npd[3];
#pragma unroll
            for (int q = 0; q < 3; q++) {
                f32x2 z  = sp2(Bm[l][q]);
                f32x2 dp = sp2(0.f);
#pragma unroll
                for (int r = 0; r < 3; r++) {
                    f32x2 wv = sp2(Wm[l][r * 3 + q]);
                    z  = pkfma(phi[r], wv, z);
                    dp = pkfma(pd[r],  wv, dp);
                }
                f32x2 tz = ftanh2(z);
                f32x2 ta = sp2(Tm[l][q]);
                nphi[q] = pkfma(tz, ta, z);
                npd[q]  = dp * pkfma(ta, pkfma(-tz, tz, one2), one2);
            }
#pragma unroll
            for (int q = 0; q < 3; q++) { phi[q] = nphi[q]; pd[q] = npd[q]; }
        }
        f32x2 z  = sp2(Bla);
        f32x2 dp = sp2(0.f);
#pragma unroll
        for (int r = 0; r < 3; r++) {
            f32x2 wv = sp2(Wla[r]);
            z  = pkfma(phi[r], wv, z);
            dp = pkfma(pd[r],  wv, dp);
        }
        f32x2 s;
        s.x = __builtin_amdgcn_rcpf(1.f + __expf(-z.x));
        s.y = __builtin_amdgcn_rcpf(1.f + __expf(-z.y));
        f32x2 prod = dp * s * (one2 - s);
        if (e == 0) {
            p0 = prod;
        } else {
            sT[lane][mm]      = p0.x * prod.x;
            sT[64 + lane][mm] = p0.y * prod.y;
        }
    }
    __syncthreads();

    // cooperative coalesced write: sT (128 n x 64 m) -> P0h/P0l[j][n][m]
    const size_t base = ((size_t)j * N_PTS + n0) * M_DIM + mc * 64;
#pragma unroll
    for (int it = 0; it < 4; it++) {
        const int idx = it * 512 + t;
        const int row = idx >> 4;
        const int c4  = idx & 15;
        float4 v;
        v.x = sT[row][c4 * 4 + 0];
        v.y = sT[row][c4 * 4 + 1];
        v.z = sT[row][c4 * 4 + 2];
        v.w = sT[row][c4 * 4 + 3];
        unsigned uh0, ul0, uh1, ul1, uh2, ul2, uh3, ul3;
        split1(v.x, uh0, ul0);
        split1(v.y, uh1, ul1);
        split1(v.z, uh2, ul2);
        split1(v.w, uh3, ul3);
        uint2 hp, lp;
        hp.x = __builtin_amdgcn_perm(uh1, uh0, 0x07060302u);
        hp.y = __builtin_amdgcn_perm(uh3, uh2, 0x07060302u);
        lp.x = __builtin_amdgcn_perm(ul1, ul0, 0x07060302u);
        lp.y = __builtin_amdgcn_perm(ul3, ul2, 0x07060302u);
        *(uint2*)(P0h + base + (size_t)row * M_DIM + c4 * 4) = hp;
        *(uint2*)(P0l + base + (size_t)row * M_DIM + c4 * 4) = lp;
    }
}

// ---------------- L0: 128x128 GEMM with PRE-SPLIT input (pure-copy stage) -
#define LDST 40  // LDS row stride in bf16 elems (32 + 8 pad = 80 B)

__global__ __launch_bounds__(256, 2) void k_gemm_ps(
    const unsigned short* __restrict__ Th, const unsigned short* __restrict__ Tl,
    const unsigned short* __restrict__ Bh, const unsigned short* __restrict__ Bl,
    const float* __restrict__ csum, float* __restrict__ Tout) {
    __shared__ unsigned short sAh[128 * LDST];
    __shared__ unsigned short sAl[128 * LDST];
    __shared__ unsigned short sBh[128 * LDST];
    __shared__ unsigned short sBl[128 * LDST];

    const int g  = blockIdx.z;
    const int n0 = blockIdx.x * 128;
    const int k0 = blockIdx.y * 128;
    const unsigned short* Thg = Th + (size_t)g * N_PTS * 256;
    const unsigned short* Tlg = Tl + (size_t)g * N_PTS * 256;
    const unsigned short* Bhg = Bh + (size_t)g * 65536;
    const unsigned short* Blg = Bl + (size_t)g * 65536;

    const int tid  = threadIdx.x;
    const int lane = tid & 63;
    const int w    = tid >> 6;
    const int wr   = w >> 1;
    const int wc   = w & 1;
    const int lr   = lane & 15;
    const int lk   = lane >> 4;

    f32x4 acc[4][4];
#pragma unroll
    for (int a = 0; a < 4; a++)
#pragma unroll
        for (int b = 0; b < 4; b++) acc[a][b] = (f32x4){0.f, 0.f, 0.f, 0.f};

    for (int kb = 0; kb < 256; kb += 32) {
#pragma unroll
        for (int i = 0; i < 2; i++) {
            const int idx = i * 256 + tid;
            const int row = idx >> 2;
            const int seg = idx & 3;
            const size_t src = (size_t)(n0 + row) * 256 + kb + seg * 8;
            *(uint4*)&sAh[row * LDST + seg * 8] = *(const uint4*)(Thg + src);
            *(uint4*)&sAl[row * LDST + seg * 8] = *(const uint4*)(Tlg + src);
        }
#pragma unroll
        for (int i = 0; i < 2; i++) {
            const int idx  = i * 256 + tid;
            const int krow = idx >> 2;
            const int seg  = idx & 3;
            const size_t src = (size_t)(k0 + krow) * 256 + kb + seg * 8;
            *(uint4*)&sBh[krow * LDST + seg * 8] = *(const uint4*)(Bhg + src);
            *(uint4*)&sBl[krow * LDST + seg * 8] = *(const uint4*)(Blg + src);
        }
        __syncthreads();

        s16x8 ah[4], al[4], bh[4], bl[4];
#pragma unroll
        for (int nt = 0; nt < 4; nt++) {
            const int off = (wr * 64 + nt * 16 + lr) * LDST + lk * 8;
            ah[nt] = *(const s16x8*)&sAh[off];
            al[nt] = *(const s16x8*)&sAl[off];
        }
#pragma unroll
        for (int kt = 0; kt < 4; kt++) {
            const int off = (wc * 64 + kt * 16 + lr) * LDST + lk * 8;
            bh[kt] = *(const s16x8*)&sBh[off];
            bl[kt] = *(const s16x8*)&sBl[off];
        }
#pragma unroll
        for (int nt = 0; nt < 4; nt++)
#pragma unroll
            for (int kt = 0; kt < 4; kt++) {
                acc[nt][kt] = __builtin_amdgcn_mfma_f32_16x16x32_bf16(ah[nt], bh[kt], acc[nt][kt], 0, 0, 0);
                acc[nt][kt] = __builtin_amdgcn_mfma_f32_16x16x32_bf16(ah[nt], bl[kt], acc[nt][kt], 0, 0, 0);
                acc[nt][kt] = __builtin_amdgcn_mfma_f32_16x16x32_bf16(al[nt], bh[kt], acc[nt][kt], 0, 0, 0);
            }
        __syncthreads();
    }

    float* Og = Tout + (size_t)g * N_PTS * 256;
#pragma unroll
    for (int kt = 0; kt < 4; kt++) {
        const int col = k0 + wc * 64 + kt * 16 + lr;
        const float inv = 1.0f / csum[g * 256 + col];
#pragma unroll
        for (int nt = 0; nt < 4; nt++) {
            const int rbase = n0 + wr * 64 + nt * 16 + lk * 4;
#pragma unroll
            for (int r = 0; r < 4; r++)
                Og[(size_t)(rbase + r) * 256 + col] = acc[nt][kt][r] * inv;
        }
    }
}

// ---------------- L1: 128x128 paired GEMM (fp32 in, split in stage-A) ----
__global__ __launch_bounds__(256, 2) void k_gemm(const float* __restrict__ Tin,
                                                 const unsigned short* __restrict__ Bh,
                                                 const unsigned short* __restrict__ Bl,
                                                 const float* __restrict__ csum,
                                                 float* __restrict__ Tout) {
    __shared__ unsigned short sAh[128 * LDST];
    __shared__ unsigned short sAl[128 * LDST];
    __shared__ unsigned short sBh[128 * LDST];
    __shared__ unsigned short sBl[128 * LDST];

    const int g  = blockIdx.z;
    const int n0 = blockIdx.x * 128;
    const int k0 = blockIdx.y * 128;
    const float* T0  = Tin + (size_t)(2 * g) * N_PTS * 256;
    const float* T1p = T0 + (size_t)N_PTS * 256;
    const unsigned short* Bhg = Bh + (size_t)g * 65536;
    const unsigned short* Blg = Bl + (size_t)g * 65536;

    const int tid  = threadIdx.x;
    const int lane = tid & 63;
    const int w    = tid >> 6;
    const int wr   = w >> 1;
    const int wc   = w & 1;
    const int lr   = lane & 15;
    const int lk   = lane >> 4;

    f32x4 acc[4][4];
#pragma unroll
    for (int a = 0; a < 4; a++)
#pragma unroll
        for (int b = 0; b < 4; b++) acc[a][b] = (f32x4){0.f, 0.f, 0.f, 0.f};

    for (int kb = 0; kb < 256; kb += 32) {
#pragma unroll
        for (int i = 0; i < 4; i++) {
            const int idx = i * 256 + tid;
            const int row = idx >> 3;
            const int m4  = idx & 7;
            float4 v = *(const float4*)(T0 + (size_t)(n0 + row) * 256 + kb + m4 * 4);
            float4 u = *(const float4*)(T1p + (size_t)(n0 + row) * 256 + kb + m4 * 4);
            v.x *= u.x; v.y *= u.y; v.z *= u.z; v.w *= u.w;
            unsigned uh0, ul0, uh1, ul1, uh2, ul2, uh3, ul3;
            split1(v.x, uh0, ul0);
            split1(v.y, uh1, ul1);
            split1(v.z, uh2, ul2);
            split1(v.w, uh3, ul3);
            uint2 hp, lp;
            hp.x = __builtin_amdgcn_perm(uh1, uh0, 0x07060302u);
            hp.y = __builtin_amdgcn_perm(uh3, uh2, 0x07060302u);
            lp.x = __builtin_amdgcn_perm(ul1, ul0, 0x07060302u);
            lp.y = __builtin_amdgcn_perm(ul3, ul2, 0x07060302u);
            *(uint2*)&sAh[row * LDST + m4 * 4] = hp;
            *(uint2*)&sAl[row * LDST + m4 * 4] = lp;
        }
#pragma unroll
        for (int i = 0; i < 2; i++) {
            const int idx  = i * 256 + tid;
            const int krow = idx >> 2;
            const int seg  = idx & 3;
            const size_t src = (size_t)(k0 + krow) * 256 + kb + seg * 8;
            *(uint4*)&sBh[krow * LDST + seg * 8] = *(const uint4*)(Bhg + src);
            *(uint4*)&sBl[krow * LDST + seg * 8] = *(const uint4*)(Blg + src);
        }
        __syncthreads();

        s16x8 ah[4], al[4], bh[4], bl[4];
#pragma unroll
        for (int nt = 0; nt < 4; nt++) {
            const int off = (wr * 64 + nt * 16 + lr) * LDST + lk * 8;
            ah[nt] = *(const s16x8*)&sAh[off];
            al[nt] = *(const s16x8*)&sAl[off];
        }
#pragma unroll
        for (int kt = 0; kt < 4; kt++) {
            const int off = (wc * 64 + kt * 16 + lr) * LDST + lk * 8;
            bh[kt] = *(const s16x8*)&sBh[off];
            bl[kt] = *(const s16x8*)&sBl[off];
        }
#pragma unroll
        for (int nt = 0; nt < 4; nt++)
#pragma unroll
            for (int kt = 0; kt < 4; kt++) {
                acc[nt][kt] = __builtin_amdgcn_mfma_f32_16x16x32_bf16(ah[nt], bh[kt], acc[nt][kt], 0, 0, 0);
                acc[nt][kt] = __builtin_amdgcn_mfma_f32_16x16x32_bf16(ah[nt], bl[kt], acc[nt][kt], 0, 0, 0);
                acc[nt][kt] = __builtin_amdgcn_mfma_f32_16x16x32_bf16(al[nt], bh[kt], acc[nt][kt], 0, 0, 0);
            }
        __syncthreads();
    }

    float* Og = Tout + (size_t)g * N_PTS * 256;
#pragma unroll
    for (int kt = 0; kt < 4; kt++) {
        const int col = k0 + wc * 64 + kt * 16 + lr;
        const float inv = 1.0f / csum[g * 256 + col];
#pragma unroll
        for (int nt = 0; nt < 4; nt++) {
            const int rbase = n0 + wr * 64 + nt * 16 + lk * 4;
#pragma unroll
            for (int r = 0; r < 4; r++)
                Og[(size_t)(rbase + r) * 256 + col] = acc[nt][kt][r] * inv;
        }
    }
}

// ---------------- L2-L4: 64x64-tile paired GEMM (4x grid density) --------
__global__ __launch_bounds__(256, 4) void k_gemm64(const float* __restrict__ Tin,
                                                   const unsigned short* __restrict__ Bh,
                                                   const unsigned short* __restrict__ Bl,
                                                   const float* __restrict__ csum,
                                                   float* __restrict__ Tout) {
    __shared__ unsigned short sAh[64 * LDST];
    __shared__ unsigned short sAl[64 * LDST];
    __shared__ unsigned short sBh[64 * LDST];
    __shared__ unsigned short sBl[64 * LDST];

    const int g  = blockIdx.z;
    const int n0 = blockIdx.x * 64;
    const int k0 = blockIdx.y * 64;
    const float* T0  = Tin + (size_t)(2 * g) * N_PTS * 256;
    const float* T1p = T0 + (size_t)N_PTS * 256;
    const unsigned short* Bhg = Bh + (size_t)g * 65536;
    const unsigned short* Blg = Bl + (size_t)g * 65536;

    const int tid  = threadIdx.x;
    const int lane = tid & 63;
    const int w    = tid >> 6;
    const int wr   = w >> 1;
    const int wc   = w & 1;
    const int lr   = lane & 15;
    const int lk   = lane >> 4;

    f32x4 acc[2][2];
#pragma unroll
    for (int a = 0; a < 2; a++)
#pragma unroll
        for (int b = 0; b < 2; b++) acc[a][b] = (f32x4){0.f, 0.f, 0.f, 0.f};

    for (int kb = 0; kb < 256; kb += 32) {
#pragma unroll
        for (int i = 0; i < 2; i++) {
            const int idx = i * 256 + tid;
            const int row = idx >> 3;
            const int m4  = idx & 7;
            float4 v = *(const float4*)(T0 + (size_t)(n0 + row) * 256 + kb + m4 * 4);
            float4 u = *(const float4*)(T1p + (size_t)(n0 + row) * 256 + kb + m4 * 4);
            v.x *= u.x; v.y *= u.y; v.z *= u.z; v.w *= u.w;
            unsigned uh0, ul0, uh1, ul1, uh2, ul2, uh3, ul3;
            split1(v.x, uh0, ul0);
            split1(v.y, uh1, ul1);
            split1(v.z, uh2, ul2);
            split1(v.w, uh3, ul3);
            uint2 hp, lp;
            hp.x = __builtin_amdgcn_perm(uh1, uh0, 0x07060302u);
            hp.y = __builtin_amdgcn_perm(uh3, uh2, 0x07060302u);
            lp.x = __builtin_amdgcn_perm(ul1, ul0, 0x07060302u);
            lp.y = __builtin_amdgcn_perm(ul3, ul2, 0x07060302u);
            *(uint2*)&sAh[row * LDST + m4 * 4] = hp;
            *(uint2*)&sAl[row * LDST + m4 * 4] = lp;
        }
        {
            const int krow = tid >> 2;
            const int seg  = tid & 3;
            const size_t src = (size_t)(k0 + krow) * 256 + kb + seg * 8;
            *(uint4*)&sBh[krow * LDST + seg * 8] = *(const uint4*)(Bhg + src);
            *(uint4*)&sBl[krow * LDST + seg * 8] = *(const uint4*)(Blg + src);
        }
        __syncthreads();

        s16x8 ah[2], al[2], bh[2], bl[2];
#pragma unroll
        for (int nt = 0; nt < 2; nt++) {
            const int off = (wr * 32 + nt * 16 + lr) * LDST + lk * 8;
            ah[nt] = *(const s16x8*)&sAh[off];
            al[nt] = *(const s16x8*)&sAl[off];
        }
#pragma unroll
        for (int kt = 0; kt < 2; kt++) {
            const int off = (wc * 32 + kt * 16 + lr) * LDST + lk * 8;
            bh[kt] = *(const s16x8*)&sBh[off];
            bl[kt] = *(const s16x8*)&sBl[off];
        }
#pragma unroll
        for (int nt = 0; nt < 2; nt++)
#pragma unroll
            for (int kt = 0; kt < 2; kt++) {
                acc[nt][kt] = __builtin_amdgcn_mfma_f32_16x16x32_bf16(ah[nt], bh[kt], acc[nt][kt], 0, 0, 0);
                acc[nt][kt] = __builtin_amdgcn_mfma_f32_16x16x32_bf16(ah[nt], bl[kt], acc[nt][kt], 0, 0, 0);
                acc[nt][kt] = __builtin_amdgcn_mfma_f32_16x16x32_bf16(al[nt], bh[kt], acc[nt][kt], 0, 0, 0);
            }
        __syncthreads();
    }

    float* Og = Tout + (size_t)g * N_PTS * 256;
#pragma unroll
    for (int kt = 0; kt < 2; kt++) {
        const int col = k0 + wc * 32 + kt * 16 + lr;
        const float inv = 1.0f / csum[g * 256 + col];
#pragma unroll
        for (int nt = 0; nt < 2; nt++) {
            const int rbase = n0 + wr * 32 + nt * 16 + lk * 4;
#pragma unroll
            for (int r = 0; r < 4; r++)
                Og[(size_t)(rbase + r) * 256 + col] = acc[nt][kt][r] * inv;
        }
    }
}

// ---------------- level 5: pair-product + normalized dot -----------------
__global__ void k_l5(const float* __restrict__ Tin, const float* __restrict__ a5,
                     float* __restrict__ out) {
    const int n = blockIdx.x;
    const int m = threadIdx.x;
    __shared__ float sv[256], sw[256];
    float w = sp10f(a5[m]);
    float v = Tin[(size_t)n * 256 + m] * Tin[(size_t)(N_PTS + n) * 256 + m] * w;
    sv[m] = v;
    sw[m] = w;
    __syncthreads();
    for (int s = 128; s > 0; s >>= 1) {
        if (m < s) { sv[m] += sv[m + s]; sw[m] += sw[m + s]; }
        __syncthreads();
    }
    if (m == 0) out[n] = sv[0] / sw[0];
}

extern "C" void kernel_launch(void* const* d_in, const int* in_sizes, int n_in,
                              void* d_out, int out_size, void* d_ws, size_t ws_size,
                              hipStream_t stream) {
    const float* X  = (const float*)d_in[0];
    const float* wf = (const float*)d_in[1];
    const float* wm = (const float*)d_in[2];
    const float* wl = (const float*)d_in[3];
    const float* b1 = (const float*)d_in[4];
    const float* bm = (const float*)d_in[5];
    const float* bl = (const float*)d_in[6];
    const float* af = (const float*)d_in[7];
    const float* am = (const float*)d_in[8];
    const float* a0 = (const float*)d_in[9];
    const float* a1 = (const float*)d_in[10];
    const float* a2 = (const float*)d_in[11];
    const float* a3 = (const float*)d_in[12];
    const float* a4 = (const float*)d_in[13];
    const float* a5 = (const float*)d_in[14];
    float* out = (float*)d_out;

    float* ws    = (float*)d_ws;
    float* Wpack = ws;                                 // 786432 f
    float* Xt    = Wpack + 786432;                     // 65536 f
    float* csum  = Xt + 65536;                         // 15872 f
    unsigned short* Anth = (unsigned short*)(csum + 15872);  // 62*65536 us
    unsigned short* Antl = Anth + (size_t)62 * 65536;        // 62*65536 us
    float* B0    = (float*)(Antl + (size_t)62 * 65536);      // 32*1024*256 f
    float* B1    = B0 + (size_t)32 * N_PTS * M_DIM;          // 32*1024*256 f
    // P0h/P0l alias the B1 region (consumed by L0 before L1 writes B1)
    unsigned short* P0h = (unsigned short*)B1;               // 32*1024*256 us
    unsigned short* P0l = P0h + (size_t)32 * N_PTS * M_DIM;  // 32*1024*256 us

    k_prep2<<<80, 256, 0, stream>>>(X, wf, wm, wl, b1, bm, bl, af, am, Wpack, Xt);
    k_tr<<<dim3(4, 4, 62), 256, 0, stream>>>(a0, a1, a2, a3, a4, Anth, Antl);
    k_csum_t<<<dim3(62, 64), 256, 0, stream>>>(Anth, Antl, csum);
    k_phase1<<<dim3(32, 4, 8), 512, 0, stream>>>(Xt, Wpack, P0h, P0l);

    // L0: presplit input, pure-copy staging
    k_gemm_ps<<<dim3(8, 2, 32), 256, 0, stream>>>(P0h, P0l, Anth, Antl, csum, B0);
    // L1: 128x128 paired
    k_gemm<<<dim3(8, 2, 16), 256, 0, stream>>>(B0, Anth + (size_t)32 * 65536,
                                               Antl + (size_t)32 * 65536, csum + 32 * 256, B1);
    // L2-L4: 64x64 paired (grids 512/256/128)
    k_gemm64<<<dim3(16, 4, 8), 256, 0, stream>>>(B1, Anth + (size_t)48 * 65536,
                                                 Antl + (size_t)48 * 65536, csum + 48 * 256, B0);
    k_gemm64<<<dim3(16, 4, 4), 256, 0, stream>>>(B0, Anth + (size_t)56 * 65536,
                                                 Antl + (size_t)56 * 65536, csum + 56 * 256, B1);
    k_gemm64<<<dim3(16, 4, 2), 256, 0, stream>>>(B1, Anth + (size_t)60 * 65536,
                                                 Antl + (size_t)60 * 65536, csum + 60 * 256, B0);
    // level 5
    k_l5<<<N_PTS, 256, 0, stream>>>(B0, a5, out);
}

// Round 11
// 163.126 us; speedup vs baseline: 1.8923x; 1.1238x over previous
//
#include <hip/hip_runtime.h>
#include <cstdint>
#include <cstddef>

// Problem constants
#define D_DIM 64
#define M_DIM 256
#define N_PTS 1024

typedef __attribute__((ext_vector_type(4))) float f32x4;
typedef __attribute__((ext_vector_type(2))) float f32x2;
typedef __attribute__((ext_vector_type(8))) short s16x8;

static __device__ __forceinline__ f32x2 pkfma(f32x2 a, f32x2 b, f32x2 c) {
#if __has_builtin(__builtin_elementwise_fma)
    return __builtin_elementwise_fma(a, b, c);
#else
    f32x2 r; r.x = fmaf(a.x, b.x, c.x); r.y = fmaf(a.y, b.y, c.y); return r;
#endif
}
static __device__ __forceinline__ f32x2 sp2(float s) {
    f32x2 r; r.x = s; r.y = s; return r;
}

static __device__ __forceinline__ float sp10f(float x) {
    // softplus(10x)/10, numerically stable, matches jax.nn.softplus
    float t = 10.f * x;
    return 0.1f * (fmaxf(t, 0.f) + log1pf(__expf(-fabsf(t))));
}

// packed branch-free tanh: 1 - 2/(exp2(x*2log2e)+1); single v_exp per lane
static __device__ __forceinline__ f32x2 ftanh2(f32x2 x) {
    f32x2 xs = x * sp2(2.88539008177793f);   // 2*log2(e)
    f32x2 e;
    e.x = __builtin_amdgcn_exp2f(xs.x);
    e.y = __builtin_amdgcn_exp2f(xs.y);
    f32x2 ep = e + sp2(1.f);
    f32x2 r;
    r.x = __builtin_amdgcn_rcpf(ep.x);
    r.y = __builtin_amdgcn_rcpf(ep.y);
    return pkfma(sp2(-2.f), r, sp2(1.f));
}

static __device__ __forceinline__ unsigned short f2bf(float x) {
    unsigned u = __float_as_uint(x);
    u = u + 0x7FFFu + ((u >> 16) & 1u);   // round-to-nearest-even
    return (unsigned short)(u >> 16);
}
static __device__ __forceinline__ float bf2f(unsigned short h) {
    return __uint_as_float(((unsigned)h) << 16);
}

// rne-hi / trunc-lo split of one fp32 -> (rounded-u32, lo-float-bits)
static __device__ __forceinline__ void split1(float x, unsigned& uh, unsigned& ul) {
    unsigned u = __float_as_uint(x);
    uh = u + 0x7FFFu + ((u >> 16) & 1u);               // rne in upper 16
    ul = __float_as_uint(x - __uint_as_float(uh & 0xFFFF0000u));  // exact tail
}

// map global level-group index g (0..61) -> (raw pointer, local g)
static __device__ __forceinline__ const float* map_g(int g, const float* a0, const float* a1,
                                                     const float* a2, const float* a3,
                                                     const float* a4, int& lg) {
    if (g < 32) { lg = g;      return a0; }
    if (g < 48) { lg = g - 32; return a1; }
    if (g < 56) { lg = g - 48; return a2; }
    if (g < 60) { lg = g - 56; return a3; }
    lg = g - 60; return a4;
}

// ---------------- fused prep: X-transpose + weight pack + HT transpose ---
// blocks 0..15: X transpose; 16..79: weight pack; 80..1071: HT transpose.
__global__ __launch_bounds__(256) void k_prep3(
    const float* __restrict__ X, const float* __restrict__ wf,
    const float* __restrict__ wm, const float* __restrict__ wl,
    const float* __restrict__ b1, const float* __restrict__ bm,
    const float* __restrict__ bl, const float* __restrict__ af,
    const float* __restrict__ am,
    const float* __restrict__ a0, const float* __restrict__ a1,
    const float* __restrict__ a2, const float* __restrict__ a3,
    const float* __restrict__ a4,
    float* __restrict__ Wpack, float* __restrict__ Xt,
    unsigned short* __restrict__ Anth, unsigned short* __restrict__ Antl) {
    __shared__ float tile[64][65];
    const int t = threadIdx.x;
    const int b = blockIdx.x;
    if (b < 16) {
        // transpose X: (N,D) -> Xt (D,N)
        const int n0 = b * 64;
#pragma unroll
        for (int i = 0; i < 4; i++) {
            const int f   = i * 256 + t;
            const int row = f >> 4;
            const int c4  = f & 15;
            float4 v = *(const float4*)(X + (size_t)(n0 + row) * 64 + c4 * 4);
            tile[row][c4 * 4 + 0] = v.x;
            tile[row][c4 * 4 + 1] = v.y;
            tile[row][c4 * 4 + 2] = v.z;
            tile[row][c4 * 4 + 3] = v.w;
        }
        __syncthreads();
#pragma unroll
        for (int i = 0; i < 4; i++) {
            const int f    = i * 256 + t;
            const int drow = f >> 4;
            const int c4   = f & 15;
            float4 v;
            v.x = tile[c4 * 4 + 0][drow];
            v.y = tile[c4 * 4 + 1][drow];
            v.z = tile[c4 * 4 + 2][drow];
            v.w = tile[c4 * 4 + 3][drow];
            *(float4*)(Xt + (size_t)drow * 1024 + n0 + c4 * 4) = v;
        }
        return;
    }
    if (b < 80) {
        // weight pack: record[dm] of 48 floats
        const int id = (b - 16) * 256 + t;  // 0..16383
        float r[48];
#pragma unroll
        for (int q = 0; q < 48; q++) r[q] = 0.f;
#pragma unroll
        for (int q = 0; q < 3; q++) {
            r[0 + q] = sp10f(wf[id * 3 + q]);
            r[3 + q] = b1[id * 3 + q];
            r[6 + q] = tanhf(af[id * 3 + q]);
            r[39 + q] = sp10f(wl[id * 3 + q]);
        }
#pragma unroll
        for (int l = 0; l < 2; l++) {
            const size_t b9 = ((size_t)l * 16384 + id) * 9;
            const size_t b3 = ((size_t)l * 16384 + id) * 3;
#pragma unroll
            for (int q = 0; q < 9; q++) r[9 + l * 15 + q] = sp10f(wm[b9 + q]);
#pragma unroll
            for (int q = 0; q < 3; q++) {
                r[18 + l * 15 + q] = bm[b3 + q];
                r[21 + l * 15 + q] = tanhf(am[b3 + q]);
            }
        }
        r[42] = bl[id];
        float4* o = (float4*)(Wpack + (size_t)id * 48);
#pragma unroll
        for (int q = 0; q < 12; q++) o[q] = ((float4*)r)[q];
        return;
    }
    // HT transpose + sp10 + bf16 hi/lo split: An_t[g][k][m]
    const int idx = b - 80;          // 0..991
    const int g   = idx >> 4;        // 0..61
    const int rr  = idx & 15;
    const int m0  = (rr & 3) * 64;
    const int k0  = (rr >> 2) * 64;
    int lg;
    const float* A  = map_g(g, a0, a1, a2, a3, a4, lg);
    const float* Ag = A + (size_t)lg * 65536;

#pragma unroll
    for (int i = 0; i < 4; i++) {
        const int f   = i * 256 + t;
        const int row = f >> 4;
        const int c4  = f & 15;
        float4 v = *(const float4*)(Ag + (size_t)(m0 + row) * 256 + k0 + c4 * 4);
        tile[row][c4 * 4 + 0] = v.x;
        tile[row][c4 * 4 + 1] = v.y;
        tile[row][c4 * 4 + 2] = v.z;
        tile[row][c4 * 4 + 3] = v.w;
    }
    __syncthreads();

#pragma unroll
    for (int i = 0; i < 4; i++) {
        const int f    = i * 256 + t;
        const int krow = f >> 4;
        const int c4   = f & 15;
        float v0 = sp10f(tile[c4 * 4 + 0][krow]);
        float v1 = sp10f(tile[c4 * 4 + 1][krow]);
        float v2 = sp10f(tile[c4 * 4 + 2][krow]);
        float v3 = sp10f(tile[c4 * 4 + 3][krow]);
        unsigned short h0 = f2bf(v0), h1 = f2bf(v1), h2 = f2bf(v2), h3 = f2bf(v3);
        ushort4 hi, lo;
        hi.x = h0; hi.y = h1; hi.z = h2; hi.w = h3;
        lo.x = f2bf(v0 - bf2f(h0));
        lo.y = f2bf(v1 - bf2f(h1));
        lo.z = f2bf(v2 - bf2f(h2));
        lo.w = f2bf(v3 - bf2f(h3));
        const size_t dst = (size_t)g * 65536 + (size_t)(k0 + krow) * 256 + m0 + c4 * 4;
        *(ushort4*)(Anth + dst) = hi;
        *(ushort4*)(Antl + dst) = lo;
    }
}

// column sums (over m) from transposed hi/lo rows.
__global__ void k_csum_t(const unsigned short* __restrict__ Anth,
                         const unsigned short* __restrict__ Antl,
                         float* __restrict__ csum) {
    const int g    = blockIdx.x;
    const int w    = threadIdx.x >> 6;
    const int lane = threadIdx.x & 63;
    const int k    = blockIdx.y * 4 + w;
    const size_t base = (size_t)g * 65536 + k * 256 + lane * 4;
    uint2 vh = *(const uint2*)(Anth + base);
    uint2 vl = *(const uint2*)(Antl + base);
    float s = 0.f;
    s += bf2f((unsigned short)(vh.x & 0xFFFFu)) + bf2f((unsigned short)(vh.x >> 16));
    s += bf2f((unsigned short)(vh.y & 0xFFFFu)) + bf2f((unsigned short)(vh.y >> 16));
    s += bf2f((unsigned short)(vl.x & 0xFFFFu)) + bf2f((unsigned short)(vl.x >> 16));
    s += bf2f((unsigned short)(vl.y & 0xFFFFu)) + bf2f((unsigned short)(vl.y >> 16));
    for (int off = 32; off > 0; off >>= 1) s += __shfl_down(s, off);
    if (lane == 0) csum[g * 256 + k] = s;
}

// ---------------- phase 1: wave = one (d,m) chain, 2 n per lane (packed) -
__global__ __launch_bounds__(512, 1) void k_phase1(
    const float* __restrict__ Xt, const float* __restrict__ Wpack,
    unsigned short* __restrict__ P0h, unsigned short* __restrict__ P0l) {
    __shared__ float sT[128][65];
    __shared__ float sXd[2][128];
    const int j  = blockIdx.x;        // d-pair
    const int mc = blockIdx.y;        // m-chunk of 64
    const int n0 = blockIdx.z * 128;  // n base
    const int t  = threadIdx.x;
    const int w    = __builtin_amdgcn_readfirstlane(t >> 6);
    const int lane = t & 63;

    if (t < 256)
        sXd[t >> 7][t & 127] = Xt[(size_t)(2 * j + (t >> 7)) * 1024 + n0 + (t & 127)];
    __syncthreads();

    f32x2 xe0, xe1;
    xe0.x = sXd[0][lane]; xe0.y = sXd[0][64 + lane];
    xe1.x = sXd[1][lane]; xe1.y = sXd[1][64 + lane];

    const f32x2 one2 = sp2(1.f);
    f32x2 p0;

#pragma unroll 2
    for (int it = 0; it < 16; it++) {
        const int i  = it >> 1;
        const int e  = it & 1;
        const int mm = w * 8 + i;
        const int m  = mc * 64 + mm;
        const float* __restrict__ rp =
            Wpack + (size_t)(((2 * j + e) << 8) + m) * 48;
        float W1a[3], B1a[3], T1a[3], Wm[2][9], Bm[2][3], Tm[2][3], Wla[3];
#pragma unroll
        for (int r = 0; r < 3; r++) {
            W1a[r] = rp[r];
            B1a[r] = rp[3 + r];
            T1a[r] = rp[6 + r];
            Bm[0][r] = rp[18 + r];
            Tm[0][r] = rp[21 + r];
            Bm[1][r] = rp[33 + r];
            Tm[1][r] = rp[36 + r];
            Wla[r] = rp[39 + r];
        }
#pragma unroll
        for (int q = 0; q < 9; q++) {
            Wm[0][q] = rp[9 + q];
            Wm[1][q] = rp[24 + q];
        }
        const float Bla = rp[42];

        const f32x2 x = e ? xe1 : xe0;
        f32x2 phi[3], pd[3];
#pragma unroll
        for (int r = 0; r < 3; r++) {
            f32x2 z  = pkfma(x, sp2(W1a[r]), sp2(B1a[r]));
            f32x2 tz = ftanh2(z);
            f32x2 ta = sp2(T1a[r]);
            pd[r]  = sp2(W1a[r]) * pkfma(ta, pkfma(-tz, tz, one2), one2);
            phi[r] = pkfma(tz, ta, z);
        }
#pragma unroll
        for (int l = 0; l < 2; l++) {
            f32x2 nphi[3], npd[3];
#pragma unroll
            for (int q = 0; q < 3; q++) {
                f32x2 z  = sp2(Bm[l][q]);
                f32x2 dp = sp2(0.f);
#pragma unroll
                for (int r = 0; r < 3; r++) {
                    f32x2 wv = sp2(Wm[l][r * 3 + q]);
                    z  = pkfma(phi[r], wv, z);
                    dp = pkfma(pd[r],  wv, dp);
                }
                f32x2 tz = ftanh2(z);
                f32x2 ta = sp2(Tm[l][q]);
                nphi[q] = pkfma(tz, ta, z);
                npd[q]  = dp * pkfma(ta, pkfma(-tz, tz, one2), one2);
            }
#pragma unroll
            for (int q = 0; q < 3; q++) { phi[q] = nphi[q]; pd[q] = npd[q]; }
        }
        f32x2 z  = sp2(Bla);
        f32x2 dp = sp2(0.f);
#pragma unroll
        for (int r = 0; r < 3; r++) {
            f32x2 wv = sp2(Wla[r]);
            z  = pkfma(phi[r], wv, z);
            dp = pkfma(pd[r],  wv, dp);
        }
        // sigmoid via single exp2 per component
        f32x2 zs = z * sp2(-1.4426950408889634f);
        f32x2 s;
        s.x = __builtin_amdgcn_rcpf(1.f + __builtin_amdgcn_exp2f(zs.x));
        s.y = __builtin_amdgcn_rcpf(1.f + __builtin_amdgcn_exp2f(zs.y));
        f32x2 prod = dp * s * (one2 - s);
        if (e == 0) {
            p0 = prod;
        } else {
            sT[lane][mm]      = p0.x * prod.x;
            sT[64 + lane][mm] = p0.y * prod.y;
        }
    }
    __syncthreads();

    // cooperative coalesced write: sT (128 n x 64 m) -> P0h/P0l[j][n][m]
    const size_t base = ((size_t)j * N_PTS + n0) * M_DIM + mc * 64;
#pragma unroll
    for (int it = 0; it < 4; it++) {
        const int idx = it * 512 + t;
        const int row = idx >> 4;
        const int c4  = idx & 15;
        float4 v;
        v.x = sT[row][c4 * 4 + 0];
        v.y = sT[row][c4 * 4 + 1];
        v.z = sT[row][c4 * 4 + 2];
        v.w = sT[row][c4 * 4 + 3];
        unsigned uh0, ul0, uh1, ul1, uh2, ul2, uh3, ul3;
        split1(v.x, uh0, ul0);
        split1(v.y, uh1, ul1);
        split1(v.z, uh2, ul2);
        split1(v.w, uh3, ul3);
        uint2 hp, lp;
        hp.x = __builtin_amdgcn_perm(uh1, uh0, 0x07060302u);
        hp.y = __builtin_amdgcn_perm(uh3, uh2, 0x07060302u);
        lp.x = __builtin_amdgcn_perm(ul1, ul0, 0x07060302u);
        lp.y = __builtin_amdgcn_perm(ul3, ul2, 0x07060302u);
        *(uint2*)(P0h + base + (size_t)row * M_DIM + c4 * 4) = hp;
        *(uint2*)(P0l + base + (size_t)row * M_DIM + c4 * 4) = lp;
    }
}

#define LDST 40  // LDS row stride in bf16 elems (32 + 8 pad = 80 B)

// ---------------- L0: 64x64 GEMM, PRE-SPLIT input (pure-copy stage) ------
// grid (16,4,32) = 2048 blocks; 6 blocks/CU for latency hiding.
__global__ __launch_bounds__(256, 6) void k_g64ps(
    const unsigned short* __restrict__ Th, const unsigned short* __restrict__ Tl,
    const unsigned short* __restrict__ Bh, const unsigned short* __restrict__ Bl,
    const float* __restrict__ csum, float* __restrict__ Tout) {
    __shared__ unsigned short sAh[64 * LDST];
    __shared__ unsigned short sAl[64 * LDST];
    __shared__ unsigned short sBh[64 * LDST];
    __shared__ unsigned short sBl[64 * LDST];

    const int g  = blockIdx.z;
    const int n0 = blockIdx.x * 64;
    const int k0 = blockIdx.y * 64;
    const unsigned short* Thg = Th + (size_t)g * N_PTS * 256;
    const unsigned short* Tlg = Tl + (size_t)g * N_PTS * 256;
    const unsigned short* Bhg = Bh + (size_t)g * 65536;
    const unsigned short* Blg = Bl + (size_t)g * 65536;

    const int tid  = threadIdx.x;
    const int lane = tid & 63;
    const int w    = tid >> 6;
    const int wr   = w >> 1;
    const int wc   = w & 1;
    const int lr   = lane & 15;
    const int lk   = lane >> 4;
    const int srow = tid >> 2;
    const int sseg = tid & 3;

    f32x4 acc[2][2];
#pragma unroll
    for (int a = 0; a < 2; a++)
#pragma unroll
        for (int b = 0; b < 2; b++) acc[a][b] = (f32x4){0.f, 0.f, 0.f, 0.f};

    for (int kb = 0; kb < 256; kb += 32) {
        const size_t srcA = (size_t)(n0 + srow) * 256 + kb + sseg * 8;
        const size_t srcB = (size_t)(k0 + srow) * 256 + kb + sseg * 8;
        *(uint4*)&sAh[srow * LDST + sseg * 8] = *(const uint4*)(Thg + srcA);
        *(uint4*)&sAl[srow * LDST + sseg * 8] = *(const uint4*)(Tlg + srcA);
        *(uint4*)&sBh[srow * LDST + sseg * 8] = *(const uint4*)(Bhg + srcB);
        *(uint4*)&sBl[srow * LDST + sseg * 8] = *(const uint4*)(Blg + srcB);
        __syncthreads();

        s16x8 ah[2], al[2], bh[2], bl[2];
#pragma unroll
        for (int nt = 0; nt < 2; nt++) {
            const int off = (wr * 32 + nt * 16 + lr) * LDST + lk * 8;
            ah[nt] = *(const s16x8*)&sAh[off];
            al[nt] = *(const s16x8*)&sAl[off];
        }
#pragma unroll
        for (int kt = 0; kt < 2; kt++) {
            const int off = (wc * 32 + kt * 16 + lr) * LDST + lk * 8;
            bh[kt] = *(const s16x8*)&sBh[off];
            bl[kt] = *(const s16x8*)&sBl[off];
        }
#pragma unroll
        for (int nt = 0; nt < 2; nt++)
#pragma unroll
            for (int kt = 0; kt < 2; kt++) {
                acc[nt][kt] = __builtin_amdgcn_mfma_f32_16x16x32_bf16(ah[nt], bh[kt], acc[nt][kt], 0, 0, 0);
                acc[nt][kt] = __builtin_amdgcn_mfma_f32_16x16x32_bf16(ah[nt], bl[kt], acc[nt][kt], 0, 0, 0);
                acc[nt][kt] = __builtin_amdgcn_mfma_f32_16x16x32_bf16(al[nt], bh[kt], acc[nt][kt], 0, 0, 0);
            }
        __syncthreads();
    }

    float* Og = Tout + (size_t)g * N_PTS * 256;
#pragma unroll
    for (int kt = 0; kt < 2; kt++) {
        const int col = k0 + wc * 32 + kt * 16 + lr;
        const float inv = 1.0f / csum[g * 256 + col];
#pragma unroll
        for (int nt = 0; nt < 2; nt++) {
            const int rbase = n0 + wr * 32 + nt * 16 + lk * 4;
#pragma unroll
            for (int r = 0; r < 4; r++)
                Og[(size_t)(rbase + r) * 256 + col] = acc[nt][kt][r] * inv;
        }
    }
}

// ---------------- L1-L4: 64x64-tile paired GEMM (fp32 in, split in stage) -
__global__ __launch_bounds__(256, 6) void k_gemm64(const float* __restrict__ Tin,
                                                   const unsigned short* __restrict__ Bh,
                                                   const unsigned short* __restrict__ Bl,
                                                   const float* __restrict__ csum,
                                                   float* __restrict__ Tout) {
    __shared__ unsigned short sAh[64 * LDST];
    __shared__ unsigned short sAl[64 * LDST];
    __shared__ unsigned short sBh[64 * LDST];
    __shared__ unsigned short sBl[64 * LDST];

    const int g  = blockIdx.z;
    const int n0 = blockIdx.x * 64;
    const int k0 = blockIdx.y * 64;
    const float* T0  = Tin + (size_t)(2 * g) * N_PTS * 256;
    const float* T1p = T0 + (size_t)N_PTS * 256;
    const unsigned short* Bhg = Bh + (size_t)g * 65536;
    const unsigned short* Blg = Bl + (size_t)g * 65536;

    const int tid  = threadIdx.x;
    const int lane = tid & 63;
    const int w    = tid >> 6;
    const int wr   = w >> 1;
    const int wc   = w & 1;
    const int lr   = lane & 15;
    const int lk   = lane >> 4;

    f32x4 acc[2][2];
#pragma unroll
    for (int a = 0; a < 2; a++)
#pragma unroll
        for (int b = 0; b < 2; b++) acc[a][b] = (f32x4){0.f, 0.f, 0.f, 0.f};

    for (int kb = 0; kb < 256; kb += 32) {
#pragma unroll
        for (int i = 0; i < 2; i++) {
            const int idx = i * 256 + tid;
            const int row = idx >> 3;
            const int m4  = idx & 7;
            float4 v = *(const float4*)(T0 + (size_t)(n0 + row) * 256 + kb + m4 * 4);
            float4 u = *(const float4*)(T1p + (size_t)(n0 + row) * 256 + kb + m4 * 4);
            v.x *= u.x; v.y *= u.y; v.z *= u.z; v.w *= u.w;
            unsigned uh0, ul0, uh1, ul1, uh2, ul2, uh3, ul3;
            split1(v.x, uh0, ul0);
            split1(v.y, uh1, ul1);
            split1(v.z, uh2, ul2);
            split1(v.w, uh3, ul3);
            uint2 hp, lp;
            hp.x = __builtin_amdgcn_perm(uh1, uh0, 0x07060302u);
            hp.y = __builtin_amdgcn_perm(uh3, uh2, 0x07060302u);
            lp.x = __builtin_amdgcn_perm(ul1, ul0, 0x07060302u);
            lp.y = __builtin_amdgcn_perm(ul3, ul2, 0x07060302u);
            *(uint2*)&sAh[row * LDST + m4 * 4] = hp;
            *(uint2*)&sAl[row * LDST + m4 * 4] = lp;
        }
        {
            const int krow = tid >> 2;
            const int seg  = tid & 3;
            const size_t src = (size_t)(k0 + krow) * 256 + kb + seg * 8;
            *(uint4*)&sBh[krow * LDST + seg * 8] = *(const uint4*)(Bhg + src);
            *(uint4*)&sBl[krow * LDST + seg * 8] = *(const uint4*)(Blg + src);
        }
        __syncthreads();

        s16x8 ah[2], al[2], bh[2], bl[2];
#pragma unroll
        for (int nt = 0; nt < 2; nt++) {
            const int off = (wr * 32 + nt * 16 + lr) * LDST + lk * 8;
            ah[nt] = *(const s16x8*)&sAh[off];
            al[nt] = *(const s16x8*)&sAl[off];
        }
#pragma unroll
        for (int kt = 0; kt < 2; kt++) {
            const int off = (wc * 32 + kt * 16 + lr) * LDST + lk * 8;
            bh[kt] = *(const s16x8*)&sBh[off];
            bl[kt] = *(const s16x8*)&sBl[off];
        }
#pragma unroll
        for (int nt = 0; nt < 2; nt++)
#pragma unroll
            for (int kt = 0; kt < 2; kt++) {
                acc[nt][kt] = __builtin_amdgcn_mfma_f32_16x16x32_bf16(ah[nt], bh[kt], acc[nt][kt], 0, 0, 0);
                acc[nt][kt] = __builtin_amdgcn_mfma_f32_16x16x32_bf16(ah[nt], bl[kt], acc[nt][kt], 0, 0, 0);
                acc[nt][kt] = __builtin_amdgcn_mfma_f32_16x16x32_bf16(al[nt], bh[kt], acc[nt][kt], 0, 0, 0);
            }
        __syncthreads();
    }

    float* Og = Tout + (size_t)g * N_PTS * 256;
#pragma unroll
    for (int kt = 0; kt < 2; kt++) {
        const int col = k0 + wc * 32 + kt * 16 + lr;
        const float inv = 1.0f / csum[g * 256 + col];
#pragma unroll
        for (int nt = 0; nt < 2; nt++) {
            const int rbase = n0 + wr * 32 + nt * 16 + lk * 4;
#pragma unroll
            for (int r = 0; r < 4; r++)
                Og[(size_t)(rbase + r) * 256 + col] = acc[nt][kt][r] * inv;
        }
    }
}

// ---------------- level 5: pair-product + normalized dot -----------------
__global__ void k_l5(const float* __restrict__ Tin, const float* __restrict__ a5,
                     float* __restrict__ out) {
    const int n = blockIdx.x;
    const int m = threadIdx.x;
    __shared__ float sv[256], sw[256];
    float w = sp10f(a5[m]);
    float v = Tin[(size_t)n * 256 + m] * Tin[(size_t)(N_PTS + n) * 256 + m] * w;
    sv[m] = v;
    sw[m] = w;
    __syncthreads();
    for (int s = 128; s > 0; s >>= 1) {
        if (m < s) { sv[m] += sv[m + s]; sw[m] += sw[m + s]; }
        __syncthreads();
    }
    if (m == 0) out[n] = sv[0] / sw[0];
}

extern "C" void kernel_launch(void* const* d_in, const int* in_sizes, int n_in,
                              void* d_out, int out_size, void* d_ws, size_t ws_size,
                              hipStream_t stream) {
    const float* X  = (const float*)d_in[0];
    const float* wf = (const float*)d_in[1];
    const float* wm = (const float*)d_in[2];
    const float* wl = (const float*)d_in[3];
    const float* b1 = (const float*)d_in[4];
    const float* bm = (const float*)d_in[5];
    const float* bl = (const float*)d_in[6];
    const float* af = (const float*)d_in[7];
    const float* am = (const float*)d_in[8];
    const float* a0 = (const float*)d_in[9];
    const float* a1 = (const float*)d_in[10];
    const float* a2 = (const float*)d_in[11];
    const float* a3 = (const float*)d_in[12];
    const float* a4 = (const float*)d_in[13];
    const float* a5 = (const float*)d_in[14];
    float* out = (float*)d_out;

    float* ws    = (float*)d_ws;
    float* Wpack = ws;                                 // 786432 f
    float* Xt    = Wpack + 786432;                     // 65536 f
    float* csum  = Xt + 65536;                         // 15872 f
    unsigned short* Anth = (unsigned short*)(csum + 15872);  // 62*65536 us
    unsigned short* Antl = Anth + (size_t)62 * 65536;        // 62*65536 us
    float* B0    = (float*)(Antl + (size_t)62 * 65536);      // 32*1024*256 f
    float* B1    = B0 + (size_t)32 * N_PTS * M_DIM;          // 32*1024*256 f
    // P0h/P0l alias the B1 region (consumed by L0 before L1 writes B1)
    unsigned short* P0h = (unsigned short*)B1;               // 32*1024*256 us
    unsigned short* P0l = P0h + (size_t)32 * N_PTS * M_DIM;  // 32*1024*256 us

    k_prep3<<<1072, 256, 0, stream>>>(X, wf, wm, wl, b1, bm, bl, af, am,
                                      a0, a1, a2, a3, a4, Wpack, Xt, Anth, Antl);
    k_csum_t<<<dim3(62, 64), 256, 0, stream>>>(Anth, Antl, csum);
    k_phase1<<<dim3(32, 4, 8), 512, 0, stream>>>(Xt, Wpack, P0h, P0l);

    // L0: presplit input, pure-copy staging, 64-tile
    k_g64ps<<<dim3(16, 4, 32), 256, 0, stream>>>(P0h, P0l, Anth, Antl, csum, B0);
    // L1-L4: 64-tile paired (grids 1024/512/256/128)
    k_gemm64<<<dim3(16, 4, 16), 256, 0, stream>>>(B0, Anth + (size_t)32 * 65536,
                                                  Antl + (size_t)32 * 65536, csum + 32 * 256, B1);
    k_gemm64<<<dim3(16, 4, 8), 256, 0, stream>>>(B1, Anth + (size_t)48 * 65536,
                                                 Antl + (size_t)48 * 65536, csum + 48 * 256, B0);
    k_gemm64<<<dim3(16, 4, 4), 256, 0, stream>>>(B0, Anth + (size_t)56 * 65536,
                                                 Antl + (size_t)56 * 65536, csum + 56 * 256, B1);
    k_gemm64<<<dim3(16, 4, 2), 256, 0, stream>>>(B1, Anth + (size_t)60 * 65536,
                                                 Antl + (size_t)60 * 65536, csum + 60 * 256, B0);
    // level 5
    k_l5<<<N_PTS, 256, 0, stream>>>(B0, a5, out);
}